// Round 14
// baseline (189.871 us; speedup 1.0000x reference)
//
#include <hip/hip_runtime.h>

// GCN encoder, CSR-free aggregation with separable norm + bf16 gather tables.
//   dinv[i] = rsqrt(deg_in[i]+1)
//   T1 = bf16( dinv * (x@W1) )                       [MFMA gemm1, fused scale+quant]
//   T2 = bf16( dinv * relu( dinv*aggsum(T1) + b1 ) ) [agg<0>]
//   T3 = bf16( dinv * aggsum(T2) )                   [agg<1>, reuses T1 buffer]
//   mu = T3@Wmu+bmu ; ls = T3@Wls+bls                [MFMA dual gemm]
// Edges bucket-sorted (256-node buckets) into bpk; each agg block owns one
// bucket and rebuilds its node-level CSR in LDS (hidden under gather stalls).
// agg floor: ~80MB L2-fill at ~1.35 TB/s service rate (R5/R13 cross-config
// evidence) -> 59us/pass is pinned. This round consolidates the prologue:
// prep fused into hist, colscan as wave-shfl scan with bbase fused via
// last-block-done (done counter zeroed upstream -> graph-replay safe).
// Lessons kept: no global-cursor atomics (R4), no interleaved slices (R7),
// no cooperative mega-kernel (R9), no narrow-grid global RMW (R11).

using uint = unsigned int;

static constexpr int FEAT = 64;
static constexpr int BN = 256;          // nodes per bucket (dlocal = 8 bits)
static constexpr int SORT_BLOCKS = 256; // edge chunks (keeps 64B sort regions)
static constexpr int SORT_TPB = 1024;   // 16 waves/block for latency hiding
static constexpr int NB_MAX = 512;      // max buckets supported in LDS
static constexpr int AGG_TPB = 1024;    // agg block = 16 waves
static constexpr int ECAP = 5120;       // bucket edge cap (mean 4096 + 16 sigma)

typedef __attribute__((ext_vector_type(8))) short bf16x8;
typedef __attribute__((ext_vector_type(4))) float f32x4;

static __device__ __forceinline__ ushort f2bf(float f) {
    uint u = __float_as_uint(f);
    u += 0x7FFFu + ((u >> 16) & 1u);
    return (ushort)(u >> 16);
}
static __device__ __forceinline__ float bf2f(ushort b) {
    return __uint_as_float(((uint)b) << 16);
}

// ---------------- hist (+ fused weight prep on the extra block) ----------------
__global__ __launch_bounds__(SORT_TPB) void hist_kernel(const int* __restrict__ dst,
                                                        int* __restrict__ hist,
                                                        const float* __restrict__ W1,
                                                        const float* __restrict__ Wmu,
                                                        const float* __restrict__ Wls,
                                                        ushort* __restrict__ w1t,
                                                        ushort* __restrict__ wmt,
                                                        ushort* __restrict__ wlt,
                                                        int* __restrict__ done,
                                                        int E, int nb) {
    if (blockIdx.x == SORT_BLOCKS) {        // prep block
        int t = threadIdx.x;
        if (t == 0) *done = 0;              // reset fused-bbase counter (replay-safe)
        for (int idx = t; idx < 64 * 128; idx += SORT_TPB) {
            int nn = idx >> 7, kk = idx & 127;
            w1t[idx] = f2bf(W1[kk * 64 + nn]);
        }
        for (int idx = t; idx < 64 * 64; idx += SORT_TPB) {
            int nn = idx >> 6, kk = idx & 63;
            wmt[idx] = f2bf(Wmu[kk * 64 + nn]);
            wlt[idx] = f2bf(Wls[kk * 64 + nn]);
        }
        return;
    }
    __shared__ int h[NB_MAX];
    for (int i = threadIdx.x; i < nb; i += SORT_TPB) h[i] = 0;
    __syncthreads();
    int chunk = (E + SORT_BLOCKS - 1) / SORT_BLOCKS;
    int beg = blockIdx.x * chunk;
    int end = min(beg + chunk, E);
    for (int e = beg + (int)threadIdx.x; e < end; e += SORT_TPB)
        atomicAdd(&h[dst[e] >> 8], 1);
    __syncthreads();
    for (int i = threadIdx.x; i < nb; i += SORT_TPB) hist[blockIdx.x * nb + i] = h[i];
}

// ---------------- colscan: wave-per-bucket shfl scan + fused bbase ----------------
// Wave handles one bucket: lane l covers blocks 4l..4l+3 (order preserved).
// Last block (done counter) scans btot -> bbase[0..nb] with one wave.
__global__ __launch_bounds__(1024) void colscan_kernel(int* __restrict__ hist,
                                                       int* __restrict__ btot,
                                                       int* __restrict__ bbase,
                                                       int* __restrict__ done, int nb) {
    __shared__ int lastflag;
    int wave = threadIdx.x >> 6;
    int lane = threadIdx.x & 63;
    int b = blockIdx.x * 16 + wave;
    if (b < nb) {
        int v[4]; int lsum = 0;
#pragma unroll
        for (int j = 0; j < 4; ++j) { v[j] = hist[(4 * lane + j) * nb + b]; lsum += v[j]; }
        int incl = lsum;
#pragma unroll
        for (int off = 1; off < 64; off <<= 1) {
            int t = __shfl_up(incl, off, 64);
            if (lane >= off) incl += t;
        }
        int e = incl - lsum;                 // exclusive over blocks
#pragma unroll
        for (int j = 0; j < 4; ++j) { hist[(4 * lane + j) * nb + b] = e; e += v[j]; }
        if (lane == 63) btot[b] = incl;
    }
    __syncthreads();
    if (threadIdx.x == 0) {
        __threadfence();
        int prev = atomicAdd(done, 1);
        lastflag = (prev == (int)gridDim.x - 1) ? 1 : 0;
    }
    __syncthreads();
    if (lastflag && wave == 0) {             // fused bbase scan (one wave)
        __threadfence();
        int v[7]; int lsum = 0;
        int base = lane * 7;
#pragma unroll
        for (int j = 0; j < 7; ++j) {
            int i = base + j;
            int x = (i < nb) ? btot[i] : 0;
            v[j] = x; lsum += x;
        }
        int incl = lsum;
#pragma unroll
        for (int off = 1; off < 64; off <<= 1) {
            int t = __shfl_up(incl, off, 64);
            if (lane >= off) incl += t;
        }
        int e = incl - lsum;
#pragma unroll
        for (int j = 0; j < 7; ++j) {
            int i = base + j;
            if (i <= nb) bbase[i] = e;
            e += v[j];
        }
    }
}

__global__ __launch_bounds__(SORT_TPB) void sort_scatter_kernel(const int* __restrict__ src,
                                                                const int* __restrict__ dst,
                                                                const int* __restrict__ hist,
                                                                const int* __restrict__ bbase,
                                                                uint* __restrict__ bpk,
                                                                int E, int nb) {
    __shared__ int cur[NB_MAX];
    int k = blockIdx.x;
    for (int i = threadIdx.x; i < nb; i += SORT_TPB) cur[i] = bbase[i] + hist[k * nb + i];
    __syncthreads();
    int chunk = (E + SORT_BLOCKS - 1) / SORT_BLOCKS;
    int beg = k * chunk;
    int end = min(beg + chunk, E);
    for (int e = beg + (int)threadIdx.x; e < end; e += SORT_TPB) {
        int s = src[e], d = dst[e];
        int pos = atomicAdd(&cur[d >> 8], 1);
        bpk[pos] = (uint)s | ((uint)(d & 255) << 17);
    }
}

// dinv from the sorted stream: one block per bucket, LDS count, zero global atomics.
__global__ __launch_bounds__(SORT_TPB) void dinv_bpk_kernel(const uint* __restrict__ bpk,
                                                            const int* __restrict__ bbase,
                                                            float* __restrict__ dinv, int n) {
    __shared__ int cnt[BN];
    int b = blockIdx.x;
    int base = b * BN;
    int t = threadIdx.x;
    int beg = bbase[b], end = bbase[b + 1];
    if (t < BN) cnt[t] = 0;
    __syncthreads();
    for (int p = beg + t; p < end; p += SORT_TPB)
        atomicAdd(&cnt[(bpk[p] >> 17) & 255], 1);
    __syncthreads();
    int node = base + t;
    if (t < BN && node < n) dinv[node] = rsqrtf((float)cnt[t] + 1.0f);
}

// ---------------- MFMA gemm1: T1 = bf16(dinv * (X@W1)) ----------------
__global__ __launch_bounds__(256) void gemm1_kernel(const float* __restrict__ X,
                                                    const ushort* __restrict__ Wt,
                                                    const float* __restrict__ dinv,
                                                    ushort* __restrict__ T1, int n) {
    int lane = threadIdx.x & 63;
    int w = threadIdx.x >> 6;
    int rowbase = blockIdx.x * 64 + w * 16;
    int nl = lane & 15;
    int kg = lane >> 4;
    int arow = min(rowbase + nl, n - 1);
    const float* xr = X + (size_t)arow * 128 + kg * 8;
    f32x4 acc0 = {0.f, 0.f, 0.f, 0.f};
    f32x4 acc1 = acc0, acc2 = acc0, acc3 = acc0;
#pragma unroll
    for (int ks = 0; ks < 4; ++ks) {
        int k0 = ks * 32;
        float4 xa = *(const float4*)(xr + k0);
        float4 xb = *(const float4*)(xr + k0 + 4);
        bf16x8 a;
        a[0] = (short)f2bf(xa.x); a[1] = (short)f2bf(xa.y);
        a[2] = (short)f2bf(xa.z); a[3] = (short)f2bf(xa.w);
        a[4] = (short)f2bf(xb.x); a[5] = (short)f2bf(xb.y);
        a[6] = (short)f2bf(xb.z); a[7] = (short)f2bf(xb.w);
        const ushort* wb = Wt + (size_t)nl * 128 + k0 + kg * 8;
        bf16x8 b0 = *(const bf16x8*)(wb);
        bf16x8 b1 = *(const bf16x8*)(wb + 16 * 128);
        bf16x8 b2 = *(const bf16x8*)(wb + 32 * 128);
        bf16x8 b3 = *(const bf16x8*)(wb + 48 * 128);
        acc0 = __builtin_amdgcn_mfma_f32_16x16x32_bf16(a, b0, acc0, 0, 0, 0);
        acc1 = __builtin_amdgcn_mfma_f32_16x16x32_bf16(a, b1, acc1, 0, 0, 0);
        acc2 = __builtin_amdgcn_mfma_f32_16x16x32_bf16(a, b2, acc2, 0, 0, 0);
        acc3 = __builtin_amdgcn_mfma_f32_16x16x32_bf16(a, b3, acc3, 0, 0, 0);
    }
#pragma unroll
    for (int r = 0; r < 4; ++r) {
        int row = rowbase + kg * 4 + r;
        if (row < n) {
            float di = dinv[row];
            ushort* out = T1 + (size_t)row * FEAT + nl;
            out[0]  = f2bf(acc0[r] * di);
            out[16] = f2bf(acc1[r] * di);
            out[32] = f2bf(acc2[r] * di);
            out[48] = f2bf(acc3[r] * di);
        }
    }
}

// ---------------- fused CSR-rebuild + aggregation ----------------
template<int MODE>
__global__ __launch_bounds__(AGG_TPB) void agg_kernel(const ushort* __restrict__ T,
                                                      const uint* __restrict__ bpk,
                                                      const int* __restrict__ bbase,
                                                      const float* __restrict__ bias,
                                                      ushort* __restrict__ Tout, int n) {
    __shared__ int lsrc[ECAP];
    __shared__ int cnt[BN];
    __shared__ int cur[BN];
    __shared__ int sc[BN];
    int b = blockIdx.x;
    int base = b * BN;
    int t = threadIdx.x;
    int beg = bbase[b], end = bbase[b + 1];
    if (t < BN) cnt[t] = 0;
    __syncthreads();
    for (int p = beg + t; p < end; p += AGG_TPB)
        atomicAdd(&cnt[(bpk[p] >> 17) & 255], 1);
    __syncthreads();
    if (t < BN) sc[t] = cnt[t];
    __syncthreads();
    for (int off = 1; off < BN; off <<= 1) {
        int u = 0;
        if (t < BN && t >= off) u = sc[t - off];
        __syncthreads();
        if (t < BN) sc[t] += u;               // inclusive scan
        __syncthreads();
    }
    if (t < BN) cur[t] = sc[t] - cnt[t];      // exclusive = write cursor
    __syncthreads();
    for (int p = beg + t; p < end; p += AGG_TPB) {
        uint e = bpk[p];
        int pos = atomicAdd(&cur[(e >> 17) & 255], 1);
        lsrc[pos] = (int)(e & 0x1FFFFu);
    }
    __syncthreads();
    int f = t & 63;
    int w = t >> 6;
    float bias_f = (MODE == 0) ? bias[f] : 0.0f;   // hoisted out of node loop
    for (int nl = w; nl < BN; nl += 16) {
        int node = base + nl;
        if (node >= n) break;                 // only last bucket; no barriers below
        int c = cnt[nl];
        int pe = sc[nl];
        int p = pe - c;
        float acc = bf2f(T[(size_t)node * FEAT + f]);   // self-loop term
        for (; p + 8 <= pe; p += 8) {
            int s0 = lsrc[p],     s1 = lsrc[p + 1], s2 = lsrc[p + 2], s3 = lsrc[p + 3];
            int s4 = lsrc[p + 4], s5 = lsrc[p + 5], s6 = lsrc[p + 6], s7 = lsrc[p + 7];
            float v0 = bf2f(T[(size_t)s0 * FEAT + f]);
            float v1 = bf2f(T[(size_t)s1 * FEAT + f]);
            float v2 = bf2f(T[(size_t)s2 * FEAT + f]);
            float v3 = bf2f(T[(size_t)s3 * FEAT + f]);
            float v4 = bf2f(T[(size_t)s4 * FEAT + f]);
            float v5 = bf2f(T[(size_t)s5 * FEAT + f]);
            float v6 = bf2f(T[(size_t)s6 * FEAT + f]);
            float v7 = bf2f(T[(size_t)s7 * FEAT + f]);
            acc += ((v0 + v1) + (v2 + v3)) + ((v4 + v5) + (v6 + v7));
        }
        for (; p < pe; ++p) acc += bf2f(T[(size_t)lsrc[p] * FEAT + f]);
        float di = rsqrtf((float)c + 1.0f);
        if (MODE == 0) {
            float h = fmaf(di, acc, bias_f);
            h = fmaxf(h, 0.0f);
            Tout[(size_t)node * FEAT + f] = f2bf(h * di);
        } else {
            Tout[(size_t)node * FEAT + f] = f2bf(di * acc);
        }
    }
}

// ---------------- MFMA dual head: mu/ls = H@W + b (H bf16) ----------------
__global__ __launch_bounds__(256) void gemm_dual_kernel(const ushort* __restrict__ H,
                                                        const ushort* __restrict__ Wmt,
                                                        const float* __restrict__ bmu,
                                                        const ushort* __restrict__ Wlt,
                                                        const float* __restrict__ bls,
                                                        float* __restrict__ mu,
                                                        float* __restrict__ ls, int n) {
    int lane = threadIdx.x & 63;
    int w = threadIdx.x >> 6;
    int rowbase = blockIdx.x * 64 + w * 16;
    int nl = lane & 15;
    int kg = lane >> 4;
    int arow = min(rowbase + nl, n - 1);
    const ushort* hr = H + (size_t)arow * 64 + kg * 8;
    f32x4 am0 = {0.f, 0.f, 0.f, 0.f};
    f32x4 am1 = am0, am2 = am0, am3 = am0;
    f32x4 al0 = am0, al1 = am0, al2 = am0, al3 = am0;
#pragma unroll
    for (int ks = 0; ks < 2; ++ks) {
        int k0 = ks * 32;
        bf16x8 a = *(const bf16x8*)(hr + k0);
        const ushort* wm = Wmt + (size_t)nl * 64 + k0 + kg * 8;
        const ushort* wl = Wlt + (size_t)nl * 64 + k0 + kg * 8;
        bf16x8 m0 = *(const bf16x8*)(wm);
        bf16x8 m1 = *(const bf16x8*)(wm + 16 * 64);
        bf16x8 m2 = *(const bf16x8*)(wm + 32 * 64);
        bf16x8 m3 = *(const bf16x8*)(wm + 48 * 64);
        bf16x8 l0 = *(const bf16x8*)(wl);
        bf16x8 l1 = *(const bf16x8*)(wl + 16 * 64);
        bf16x8 l2 = *(const bf16x8*)(wl + 32 * 64);
        bf16x8 l3 = *(const bf16x8*)(wl + 48 * 64);
        am0 = __builtin_amdgcn_mfma_f32_16x16x32_bf16(a, m0, am0, 0, 0, 0);
        am1 = __builtin_amdgcn_mfma_f32_16x16x32_bf16(a, m1, am1, 0, 0, 0);
        am2 = __builtin_amdgcn_mfma_f32_16x16x32_bf16(a, m2, am2, 0, 0, 0);
        am3 = __builtin_amdgcn_mfma_f32_16x16x32_bf16(a, m3, am3, 0, 0, 0);
        al0 = __builtin_amdgcn_mfma_f32_16x16x32_bf16(a, l0, al0, 0, 0, 0);
        al1 = __builtin_amdgcn_mfma_f32_16x16x32_bf16(a, l1, al1, 0, 0, 0);
        al2 = __builtin_amdgcn_mfma_f32_16x16x32_bf16(a, l2, al2, 0, 0, 0);
        al3 = __builtin_amdgcn_mfma_f32_16x16x32_bf16(a, l3, al3, 0, 0, 0);
    }
    float bm0 = bmu[nl], bm1 = bmu[16 + nl], bm2 = bmu[32 + nl], bm3 = bmu[48 + nl];
    float bl0 = bls[nl], bl1 = bls[16 + nl], bl2 = bls[32 + nl], bl3 = bls[48 + nl];
#pragma unroll
    for (int r = 0; r < 4; ++r) {
        int row = rowbase + kg * 4 + r;
        if (row < n) {
            float* om = mu + (size_t)row * 64 + nl;
            float* ol = ls + (size_t)row * 64 + nl;
            om[0]  = am0[r] + bm0; om[16] = am1[r] + bm1;
            om[32] = am2[r] + bm2; om[48] = am3[r] + bm3;
            ol[0]  = al0[r] + bl0; ol[16] = al1[r] + bl1;
            ol[32] = al2[r] + bl2; ol[48] = al3[r] + bl3;
        }
    }
}

extern "C" void kernel_launch(void* const* d_in, const int* in_sizes, int n_in,
                              void* d_out, int out_size, void* d_ws, size_t ws_size,
                              hipStream_t stream) {
    const float* x   = (const float*)d_in[0];
    const int*   ei  = (const int*)d_in[1];
    const float* W1  = (const float*)d_in[2];
    const float* b1  = (const float*)d_in[3];
    const float* Wmu = (const float*)d_in[4];
    const float* bmu = (const float*)d_in[5];
    const float* Wls = (const float*)d_in[6];
    const float* bls = (const float*)d_in[7];

    const int N = in_sizes[0] / 128;
    const int E = in_sizes[1] / 2;
    const int* src = ei;
    const int* dst = ei + E;

    const int nb = (N + BN - 1) / BN;   // 391 buckets (<= NB_MAX)

    float*  dinv   = (float*)d_ws;                      // N
    int*    hist   = (int*)(dinv + N);                  // SORT_BLOCKS*nb
    int*    btot   = hist + SORT_BLOCKS * nb;           // nb (padded)
    int*    bbase  = btot + ((nb + 63) & ~63);          // nb+1 (padded)
    int*    done   = bbase + ((nb + 1 + 63) & ~63);     // 1 (padded)
    uint*   bpk    = (uint*)(done + 64);                // E
    ushort* T1     = (ushort*)(bpk + E);                // N*64 bf16 (T1, then T3)
    ushort* T2     = T1 + (size_t)N * FEAT;             // N*64 bf16
    ushort* w1t    = T2 + (size_t)N * FEAT;             // 64*128 bf16
    ushort* wmt    = w1t + 64 * 128;                    // 64*64 bf16
    ushort* wlt    = wmt + 64 * 64;                     // 64*64 bf16

    float* mu_out = (float*)d_out;                      // N*64
    float* ls_out = mu_out + (size_t)N * FEAT;          // N*64

    const int TB = 256;
    int grid_g = (N + 63) / 64;
    int grid_cs = (nb + 15) / 16;       // colscan: 16 buckets (waves) per block

    // ---- bucket sort (hist + fused prep/done-reset; wave-scan colscan + fused bbase) ----
    hist_kernel<<<SORT_BLOCKS + 1, SORT_TPB, 0, stream>>>(dst, hist, W1, Wmu, Wls,
                                                          w1t, wmt, wlt, done, E, nb);
    colscan_kernel<<<grid_cs, 1024, 0, stream>>>(hist, btot, bbase, done, nb);
    sort_scatter_kernel<<<SORT_BLOCKS, SORT_TPB, 0, stream>>>(src, dst, hist, bbase, bpk, E, nb);
    dinv_bpk_kernel<<<nb, SORT_TPB, 0, stream>>>(bpk, bbase, dinv, N);

    // ---- T1 = bf16(dinv * (x@W1)) via MFMA ----
    gemm1_kernel<<<grid_g, TB, 0, stream>>>(x, w1t, dinv, T1, N);

    // ---- T2 = bf16(dinv * relu(dinv*aggsum(T1) + b1)) ----
    agg_kernel<0><<<nb, AGG_TPB, 0, stream>>>(T1, bpk, bbase, b1, T2, N);

    // ---- T3 = bf16(dinv * aggsum(T2))  (reuses T1 buffer) ----
    agg_kernel<1><<<nb, AGG_TPB, 0, stream>>>(T2, bpk, bbase, nullptr, T1, N);

    // ---- heads via MFMA: mu/ls from bf16 T3 ----
    gemm_dual_kernel<<<grid_g, TB, 0, stream>>>(T1, wmt, bmu, wlt, bls, mu_out, ls_out, N);
}